// Round 4
// baseline (8283.067 us; speedup 1.0000x reference)
//
#include <hip/hip_runtime.h>
#include <hip/hip_bf16.h>

typedef float f32x4 __attribute__((ext_vector_type(4)));
typedef __bf16 bf16x8 __attribute__((ext_vector_type(8)));

#define B_SZ 2048
#define T_IN 48
#define FEAT 64
#define UNITS 1024
#define GCOLS 4096   // 4*UNITS
#define OUT_STEPS 64
#define KWARM 1088   // UNITS + FEAT

// Gate-major column permutation: c' = 64*Bk + 16*g + u  (Bk = 64-col half-block, g = gate, u = unit-low)
// original (Keras i,f,g,o) column: oc = g*1024 + (Bk*16 + u)
__device__ __forceinline__ int oc_of(int c) {
    return (((c >> 4) & 3) * UNITS) + ((c >> 6) * 16) + (c & 15);
}

typedef __attribute__((address_space(1))) const void gas_t;
typedef __attribute__((address_space(3))) void las_t;

__device__ __forceinline__ void gl_lds16(const void* g, void* l) {
    __builtin_amdgcn_global_load_lds((gas_t*)g, (las_t*)l, 16, 0, 0);
}
__device__ __forceinline__ float sigm(float x) {
    return __builtin_amdgcn_rcpf(1.0f + __expf(-x));
}
__device__ __forceinline__ float tanh_fast(float x) {
    float e = __expf(2.0f * x);
    return 1.0f - 2.0f * __builtin_amdgcn_rcpf(e + 1.0f);
}

// ---------- precompute kernels (unchanged, correctness-proven) ----------

__global__ __launch_bounds__(256) void reorder_UW(const float* __restrict__ U, const float* __restrict__ W,
                                                  __hip_bfloat16* __restrict__ UTw) {
    __shared__ __hip_bfloat16 t[64][64];
    const int k0 = blockIdx.x * 64;   // 17 tiles
    const int c0 = blockIdx.y * 64;   // 64 tiles
    const int tid = threadIdx.x;
#pragma unroll
    for (int i = 0; i < 16; ++i) {
        int idx = tid + i * 256;
        int rk = idx >> 6, cc = idx & 63;
        int k = k0 + rk, c = c0 + cc;
        int oc = oc_of(c);
        float v = (k < UNITS) ? U[(size_t)k * GCOLS + oc] : W[(size_t)(k - UNITS) * GCOLS + oc];
        t[rk][cc] = __float2bfloat16(v);
    }
    __syncthreads();
#pragma unroll
    for (int i = 0; i < 16; ++i) {
        int idx = tid + i * 256;
        int rc = idx >> 6, kk = idx & 63;
        UTw[(size_t)(c0 + rc) * KWARM + k0 + kk] = t[kk][rc];
    }
}

__global__ __launch_bounds__(256) void transpose_Wd(const float* __restrict__ Wd, __hip_bfloat16* __restrict__ WdT) {
    __shared__ __hip_bfloat16 t[64][64];
    const int k0 = blockIdx.x * 64;  // 16 blocks
    const int tid = threadIdx.x;
#pragma unroll
    for (int i = 0; i < 16; ++i) {
        int idx = tid + i * 256;
        int rk = idx >> 6, ff = idx & 63;
        t[rk][ff] = __float2bfloat16(Wd[(size_t)(k0 + rk) * FEAT + ff]);
    }
    __syncthreads();
#pragma unroll
    for (int i = 0; i < 16; ++i) {
        int idx = tid + i * 256;
        int rf = idx >> 6, kk = idx & 63;
        WdT[(size_t)rf * UNITS + k0 + kk] = t[kk][rf];
    }
}

__global__ __launch_bounds__(256) void build_UTdec(const __hip_bfloat16* __restrict__ UTw,
                                                   const __hip_bfloat16* __restrict__ WdT,
                                                   __hip_bfloat16* __restrict__ UTd) {
    __shared__ float Wl[64][16];
    const int k = blockIdx.x * 256 + threadIdx.x;  // 4 blocks
    const int c0 = blockIdx.y * 16;                // 256 blocks
    const int tid = threadIdx.x;
#pragma unroll
    for (int i = 0; i < 4; ++i) {
        int idx = tid + i * 256;
        int f = idx >> 4, cc = idx & 15;
        Wl[f][cc] = __bfloat162float(UTw[(size_t)(c0 + cc) * KWARM + UNITS + f]);
    }
    __syncthreads();
    float acc[16];
#pragma unroll
    for (int cc = 0; cc < 16; ++cc) acc[cc] = 0.f;
    for (int f = 0; f < 64; ++f) {
        float wd = __bfloat162float(WdT[(size_t)f * UNITS + k]);
#pragma unroll
        for (int cc = 0; cc < 16; ++cc) acc[cc] += wd * Wl[f][cc];
    }
#pragma unroll
    for (int cc = 0; cc < 16; ++cc) {
        float uv = __bfloat162float(UTw[(size_t)(c0 + cc) * KWARM + k]);
        UTd[(size_t)(c0 + cc) * UNITS + k] = __float2bfloat16(uv + acc[cc]);
    }
}

__global__ __launch_bounds__(256) void build_bias(const float* __restrict__ b, const float* __restrict__ bd,
                                                  const __hip_bfloat16* __restrict__ UTw,
                                                  float* __restrict__ bw, float* __restrict__ bdc) {
    const int c = blockIdx.x * 256 + threadIdx.x;  // 16 blocks
    const int oc = oc_of(c);
    float base = b[oc];
    float s = 0.f;
    for (int f = 0; f < FEAT; ++f) s += bd[f] * __bfloat162float(UTw[(size_t)c * KWARM + UNITS + f]);
    bw[c] = base;
    bdc[c] = base + s;
}

__global__ void convert_x(const float* __restrict__ x, __hip_bfloat16* __restrict__ xb, int n) {
    int i = blockIdx.x * blockDim.x + threadIdx.x;
    if (i < n) xb[i] = __float2bfloat16(x[i]);
}

// ---------- fused LSTM step ----------
// R4: A-only LDS (32KB dbuf, swizzled gl_lds) -> 3 blocks/CU; B and Wd read
// DIRECTLY from global (L2-resident via 8x8-rectangle XCD swizzle) into regs,
// one iter ahead; pred spread across nb=0..3 (ni=nb) for balance.
template <bool WARM, bool PRED>
__global__ __launch_bounds__(256, 3) void lstm_step(
    const __hip_bfloat16* __restrict__ hin,          // [2048][1024]
    const __hip_bfloat16* __restrict__ xbf, int t,   // [2048][48][64] (WARM)
    const __hip_bfloat16* __restrict__ UT,           // [4096][KD]
    const float* __restrict__ bias,                  // [4096] (c'-indexed)
    float* __restrict__ cst,                         // [2048][1024]
    __hip_bfloat16* __restrict__ hout,               // [2048][1024]
    const __hip_bfloat16* __restrict__ WdT,          // [64][1024] (PRED)
    const float* __restrict__ bd,                    // [64] (PRED)
    float* __restrict__ out, int tstep)              // [2048][64][64] (PRED)
{
    constexpr int KD = WARM ? KWARM : UNITS;
    constexpr int NKT = KD / 64;

    __shared__ alignas(16) __hip_bfloat16 Al[2 * 8192];   // 32 KB

    const int tid = threadIdx.x;
    const int lane = tid & 63;
    const int wv = tid >> 6;
    const int wr = wv >> 1, wc = wv & 1;
    const int bid = blockIdx.x;
    // 8x8 rectangle per XCD: per-XCD footprint = 8 A-slices (2MB) + 8 B-slices (2MB)
    const int x = bid & 7;
    const int bl = bid >> 3;
    const int mb = ((x >> 2) << 3) + (bl >> 3);
    const int nb = ((x & 3) << 3) + (bl & 7);
    const int m0 = mb * 128;
    const int n0 = nb * 128;
    const bool doPred = PRED && (nb < 4);

    f32x4 acc[4][4] = {};
    f32x4 accp[2] = {};

    const int lrow = lane >> 3;
    const int scol = ((lane & 7) * 16) ^ (lrow << 4);   // swizzled source byte col (A staging)

    // A staging bases (k-advance folds into imm offsets)
    const char* aS[4]; const char* xS[4];
#pragma unroll
    for (int r = 0; r < 4; ++r) {
        int row = (r * 4 + wv) * 8 + lrow;
        aS[r] = (const char*)hin + (size_t)(m0 + row) * (UNITS * 2) + scol;
        if (WARM) xS[r] = (const char*)xbf + (size_t)(m0 + row) * (T_IN * FEAT * 2) + (size_t)t * (FEAT * 2) + scol;
    }

    const int ar = lane & 15;
    const int ko = (lane >> 4) << 3;
    const int swz = (ar & 7) << 3;

    // B direct-load bases: frag ni = UT[n0+64wc+16ni+ar][kt*64 + kk*32 + ko .. +8)
    const char* bB[4];
#pragma unroll
    for (int ni = 0; ni < 4; ++ni)
        bB[ni] = (const char*)UT + ((size_t)(n0 + 64 * wc + 16 * ni + ar) * KD + ko) * 2;
    const char* wB = nullptr;
    if (PRED && doPred)
        wB = (const char*)WdT + ((size_t)(16 * nb + ar) * UNITS + ko) * 2;

    // epilogue geometry; bias preloaded (drained by first vmcnt)
    const int u16 = lane & 15;
    const int unit = (nb * 2 + wc) * 16 + u16;
    const int rbase = m0 + 64 * wr + ((lane >> 4) << 2);
    float bv[4];
#pragma unroll
    for (int g = 0; g < 4; ++g) bv[g] = bias[n0 + 64 * wc + 16 * g + u16];
    float bdv = 0.f;
    if (PRED && doPred) bdv = bd[16 * nb + u16];

    auto stageA = [&](int kt) {
        const int buf = kt & 1;
#pragma unroll
        for (int r = 0; r < 4; ++r) {
            const char* s = (WARM && kt == NKT - 1) ? xS[r] : (aS[r] + kt * 128);
            gl_lds16(s, (char*)Al + buf * 16384 + (r * 4 + wv) * 1024);
        }
    };

    bf16x8 Bf[8];
    bf16x8 Wf[2];
    auto loadB = [&](int kt) {
#pragma unroll
        for (int kk = 0; kk < 2; ++kk)
#pragma unroll
            for (int ni = 0; ni < 4; ++ni)
                Bf[kk * 4 + ni] = *reinterpret_cast<const bf16x8*>(bB[ni] + kt * 128 + kk * 64);
        if (PRED && doPred) {
#pragma unroll
            for (int kk = 0; kk < 2; ++kk)
                Wf[kk] = *reinterpret_cast<const bf16x8*>(wB + kt * 128 + kk * 64);
        }
    };

    auto compute = [&](int kt) {
        const int buf = kt & 1;
#pragma unroll
        for (int kk = 0; kk < 2; ++kk) {
            bf16x8 af[4];
#pragma unroll
            for (int mi = 0; mi < 4; ++mi)
                af[mi] = *reinterpret_cast<const bf16x8*>(&Al[buf * 8192 + (64 * wr + 16 * mi + ar) * 64 + ((32 * kk + ko) ^ swz)]);
#pragma unroll
            for (int mi = 0; mi < 4; ++mi)
#pragma unroll
                for (int ni = 0; ni < 4; ++ni)
                    acc[mi][ni] = __builtin_amdgcn_mfma_f32_16x16x32_bf16(af[mi], Bf[kk * 4 + ni], acc[mi][ni], 0, 0, 0);
            if (PRED && doPred) {
#pragma unroll
                for (int pi = 0; pi < 2; ++pi)
                    accp[pi] = __builtin_amdgcn_mfma_f32_16x16x32_bf16(af[2 * wc + pi], Wf[kk], accp[pi], 0, 0, 0);
            }
        }
    };

    // ---- pipelined K loop: A(kt) in LDS, B(kt) in regs; prefetch both for kt+1 ----
    stageA(0);
    loadB(0);
#pragma unroll
    for (int kt = 0; kt < NKT - 1; ++kt) {
        stageA(kt + 1);
        // wait everything except the 4 newest (A(kt+1) gl_lds): A(kt)+B(kt) done
        asm volatile("s_waitcnt vmcnt(4) lgkmcnt(0)" ::: "memory");
        __builtin_amdgcn_s_barrier();
        compute(kt);
        loadB(kt + 1);                      // overwrites Bf after last use (compiler-sequenced)
        __builtin_amdgcn_s_barrier();       // WAR on Al: keep waves within one iter
    }
    // final iter: prefetch c-state in the slot where A-staging would be
    float cv[16];
#pragma unroll
    for (int mi = 0; mi < 4; ++mi)
#pragma unroll
        for (int reg = 0; reg < 4; ++reg)
            cv[mi * 4 + reg] = cst[(size_t)(rbase + 16 * mi + reg) * UNITS + unit];
    asm volatile("s_waitcnt vmcnt(16) lgkmcnt(0)" ::: "memory");
    __builtin_amdgcn_s_barrier();
    compute(NKT - 1);

    // ---- shuffle-free gate epilogue: acc[mi][g] are i,f,g,o of this lane's unit ----
#pragma unroll
    for (int mi = 0; mi < 4; ++mi)
#pragma unroll
        for (int reg = 0; reg < 4; ++reg) {
            float zi = acc[mi][0][reg] + bv[0];
            float zf = acc[mi][1][reg] + bv[1];
            float zg = acc[mi][2][reg] + bv[2];
            float zo = acc[mi][3][reg] + bv[3];
            float cn = sigm(zf) * cv[mi * 4 + reg] + sigm(zi) * tanh_fast(zg);
            size_t idx = (size_t)(rbase + 16 * mi + reg) * UNITS + unit;
            cst[idx] = cn;
            hout[idx] = __float2bfloat16(sigm(zo) * tanh_fast(cn));
        }

    if (PRED && doPred) {
#pragma unroll
        for (int pi = 0; pi < 2; ++pi) {
            const int prow = m0 + 64 * wr + 32 * wc + 16 * pi + ((lane >> 4) << 2);
            f32x4 v = accp[pi];
#pragma unroll
            for (int reg = 0; reg < 4; ++reg)
                out[(size_t)(prow + reg) * (OUT_STEPS * FEAT) + (size_t)tstep * FEAT + (16 * nb + u16)] = v[reg] + bdv;
        }
    }
}

// ---------- host ----------
extern "C" void kernel_launch(void* const* d_in, const int* in_sizes, int n_in,
                              void* d_out, int out_size, void* d_ws, size_t ws_size,
                              hipStream_t stream) {
    const float* inputs = (const float*)d_in[0];
    const float* W  = (const float*)d_in[1];
    const float* U  = (const float*)d_in[2];
    const float* b  = (const float*)d_in[3];
    const float* Wd = (const float*)d_in[4];
    const float* bd = (const float*)d_in[5];
    float* out = (float*)d_out;

    char* ws = (char*)d_ws;
    size_t off = 0;
    auto alloc = [&](size_t bytes) { char* p = ws + off; off = (off + bytes + 255) & ~255ULL; return p; };
    __hip_bfloat16* UTw = (__hip_bfloat16*)alloc((size_t)GCOLS * KWARM * 2);
    __hip_bfloat16* UTd = (__hip_bfloat16*)alloc((size_t)GCOLS * UNITS * 2);
    __hip_bfloat16* WdT = (__hip_bfloat16*)alloc((size_t)FEAT * UNITS * 2);
    __hip_bfloat16* Xbf = (__hip_bfloat16*)alloc((size_t)B_SZ * T_IN * FEAT * 2);
    __hip_bfloat16* hA  = (__hip_bfloat16*)alloc((size_t)B_SZ * UNITS * 2);
    __hip_bfloat16* hB  = (__hip_bfloat16*)alloc((size_t)B_SZ * UNITS * 2);
    float* cst = (float*)alloc((size_t)B_SZ * UNITS * 4);
    float* bw  = (float*)alloc(GCOLS * 4);
    float* bdc = (float*)alloc(GCOLS * 4);

    hipMemsetAsync(cst, 0, (size_t)B_SZ * UNITS * 4, stream);
    hipMemsetAsync(hA, 0, (size_t)B_SZ * UNITS * 2, stream);

    dim3 blk(256);
    reorder_UW<<<dim3(17, 64), blk, 0, stream>>>(U, W, UTw);
    transpose_Wd<<<dim3(16), blk, 0, stream>>>(Wd, WdT);
    build_UTdec<<<dim3(4, 256), blk, 0, stream>>>(UTw, WdT, UTd);
    build_bias<<<dim3(16), blk, 0, stream>>>(b, bd, UTw, bw, bdc);
    {
        int n = B_SZ * T_IN * FEAT;
        convert_x<<<dim3((n + 255) / 256), blk, 0, stream>>>(inputs, Xbf, n);
    }

    const __hip_bfloat16* cur = hA;
    __hip_bfloat16* nxt = hB;
    for (int t = 0; t < T_IN; ++t) {
        lstm_step<true, false><<<dim3(512), blk, 0, stream>>>(cur, Xbf, t, UTw, bw, cst, nxt,
                                                              nullptr, nullptr, nullptr, 0);
        __hip_bfloat16* tmp = (__hip_bfloat16*)cur; cur = nxt; nxt = tmp;
    }
    // decode: kernel t consumes h_{t-1} (writes pred_{t-1}) and produces h_t
    for (int t = 1; t <= OUT_STEPS; ++t) {
        lstm_step<false, true><<<dim3(512), blk, 0, stream>>>(cur, nullptr, 0, UTd, bdc, cst, nxt,
                                                              WdT, bd, out, t - 1);
        __hip_bfloat16* tmp = (__hip_bfloat16*)cur; cur = nxt; nxt = tmp;
    }
}

// Round 5
// 7965.073 us; speedup vs baseline: 1.0399x; 1.0399x over previous
//
#include <hip/hip_runtime.h>
#include <hip/hip_bf16.h>

typedef float f32x4 __attribute__((ext_vector_type(4)));
typedef __bf16 bf16x8 __attribute__((ext_vector_type(8)));

#define B_SZ 2048
#define T_IN 48
#define FEAT 64
#define UNITS 1024
#define GCOLS 4096   // 4*UNITS
#define OUT_STEPS 64
#define KWARM 1088   // UNITS + FEAT

// Gate-major column permutation: c' = 64*Bk + 16*g + u  (Bk = 64-col half-block, g = gate, u = unit-low)
// original (Keras i,f,g,o) column: oc = g*1024 + (Bk*16 + u)
__device__ __forceinline__ int oc_of(int c) {
    return (((c >> 4) & 3) * UNITS) + ((c >> 6) * 16) + (c & 15);
}

typedef __attribute__((address_space(1))) const void gas_t;
typedef __attribute__((address_space(3))) void las_t;

__device__ __forceinline__ void gl_lds16(const void* g, void* l) {
    __builtin_amdgcn_global_load_lds((gas_t*)g, (las_t*)l, 16, 0, 0);
}
__device__ __forceinline__ float sigm(float x) {
    return __builtin_amdgcn_rcpf(1.0f + __expf(-x));
}
__device__ __forceinline__ float tanh_fast(float x) {
    float e = __expf(2.0f * x);
    return 1.0f - 2.0f * __builtin_amdgcn_rcpf(e + 1.0f);
}

// ---------- precompute kernels (unchanged, correctness-proven) ----------

__global__ __launch_bounds__(256) void reorder_UW(const float* __restrict__ U, const float* __restrict__ W,
                                                  __hip_bfloat16* __restrict__ UTw) {
    __shared__ __hip_bfloat16 t[64][64];
    const int k0 = blockIdx.x * 64;   // 17 tiles
    const int c0 = blockIdx.y * 64;   // 64 tiles
    const int tid = threadIdx.x;
#pragma unroll
    for (int i = 0; i < 16; ++i) {
        int idx = tid + i * 256;
        int rk = idx >> 6, cc = idx & 63;
        int k = k0 + rk, c = c0 + cc;
        int oc = oc_of(c);
        float v = (k < UNITS) ? U[(size_t)k * GCOLS + oc] : W[(size_t)(k - UNITS) * GCOLS + oc];
        t[rk][cc] = __float2bfloat16(v);
    }
    __syncthreads();
#pragma unroll
    for (int i = 0; i < 16; ++i) {
        int idx = tid + i * 256;
        int rc = idx >> 6, kk = idx & 63;
        UTw[(size_t)(c0 + rc) * KWARM + k0 + kk] = t[kk][rc];
    }
}

__global__ __launch_bounds__(256) void transpose_Wd(const float* __restrict__ Wd, __hip_bfloat16* __restrict__ WdT) {
    __shared__ __hip_bfloat16 t[64][64];
    const int k0 = blockIdx.x * 64;  // 16 blocks
    const int tid = threadIdx.x;
#pragma unroll
    for (int i = 0; i < 16; ++i) {
        int idx = tid + i * 256;
        int rk = idx >> 6, ff = idx & 63;
        t[rk][ff] = __float2bfloat16(Wd[(size_t)(k0 + rk) * FEAT + ff]);
    }
    __syncthreads();
#pragma unroll
    for (int i = 0; i < 16; ++i) {
        int idx = tid + i * 256;
        int rf = idx >> 6, kk = idx & 63;
        WdT[(size_t)rf * UNITS + k0 + kk] = t[kk][rf];
    }
}

__global__ __launch_bounds__(256) void build_UTdec(const __hip_bfloat16* __restrict__ UTw,
                                                   const __hip_bfloat16* __restrict__ WdT,
                                                   __hip_bfloat16* __restrict__ UTd) {
    __shared__ float Wl[64][16];
    const int k = blockIdx.x * 256 + threadIdx.x;  // 4 blocks
    const int c0 = blockIdx.y * 16;                // 256 blocks
    const int tid = threadIdx.x;
#pragma unroll
    for (int i = 0; i < 4; ++i) {
        int idx = tid + i * 256;
        int f = idx >> 4, cc = idx & 15;
        Wl[f][cc] = __bfloat162float(UTw[(size_t)(c0 + cc) * KWARM + UNITS + f]);
    }
    __syncthreads();
    float acc[16];
#pragma unroll
    for (int cc = 0; cc < 16; ++cc) acc[cc] = 0.f;
    for (int f = 0; f < 64; ++f) {
        float wd = __bfloat162float(WdT[(size_t)f * UNITS + k]);
#pragma unroll
        for (int cc = 0; cc < 16; ++cc) acc[cc] += wd * Wl[f][cc];
    }
#pragma unroll
    for (int cc = 0; cc < 16; ++cc) {
        float uv = __bfloat162float(UTw[(size_t)(c0 + cc) * KWARM + k]);
        UTd[(size_t)(c0 + cc) * UNITS + k] = __float2bfloat16(uv + acc[cc]);
    }
}

__global__ __launch_bounds__(256) void build_bias(const float* __restrict__ b, const float* __restrict__ bd,
                                                  const __hip_bfloat16* __restrict__ UTw,
                                                  float* __restrict__ bw, float* __restrict__ bdc) {
    const int c = blockIdx.x * 256 + threadIdx.x;  // 16 blocks
    const int oc = oc_of(c);
    float base = b[oc];
    float s = 0.f;
    for (int f = 0; f < FEAT; ++f) s += bd[f] * __bfloat162float(UTw[(size_t)c * KWARM + UNITS + f]);
    bw[c] = base;
    bdc[c] = base + s;
}

__global__ void convert_x(const float* __restrict__ x, __hip_bfloat16* __restrict__ xb, int n) {
    int i = blockIdx.x * blockDim.x + threadIdx.x;
    if (i < n) xb[i] = __float2bfloat16(x[i]);
}

// ---------- fused LSTM step ----------
// R5 = R4 structure (A-only 32KB LDS, B/Wd direct-from-L2 into regs, 8x8 XCD
// rectangle, pred spread over nb<4) with the register cap REMOVED — R4's
// __launch_bounds__(256,3) forced VGPR=84 -> acc spill to scratch (+45MB HBM
// writes). Plain bound lets the allocator use ~160-190 regs, no spill.
template <bool WARM, bool PRED>
__global__ __launch_bounds__(256) void lstm_step(
    const __hip_bfloat16* __restrict__ hin,          // [2048][1024]
    const __hip_bfloat16* __restrict__ xbf, int t,   // [2048][48][64] (WARM)
    const __hip_bfloat16* __restrict__ UT,           // [4096][KD]
    const float* __restrict__ bias,                  // [4096] (c'-indexed)
    float* __restrict__ cst,                         // [2048][1024]
    __hip_bfloat16* __restrict__ hout,               // [2048][1024]
    const __hip_bfloat16* __restrict__ WdT,          // [64][1024] (PRED)
    const float* __restrict__ bd,                    // [64] (PRED)
    float* __restrict__ out, int tstep)              // [2048][64][64] (PRED)
{
    constexpr int KD = WARM ? KWARM : UNITS;
    constexpr int NKT = KD / 64;

    __shared__ alignas(16) __hip_bfloat16 Al[2 * 8192];   // 32 KB

    const int tid = threadIdx.x;
    const int lane = tid & 63;
    const int wv = tid >> 6;
    const int wr = wv >> 1, wc = wv & 1;
    const int bid = blockIdx.x;
    // 8x8 rectangle per XCD: per-XCD footprint = 8 A-slices (2MB) + 8 B-slices (2MB)
    const int x = bid & 7;
    const int bl = bid >> 3;
    const int mb = ((x >> 2) << 3) + (bl >> 3);
    const int nb = ((x & 3) << 3) + (bl & 7);
    const int m0 = mb * 128;
    const int n0 = nb * 128;
    const bool doPred = PRED && (nb < 4);

    f32x4 acc[4][4] = {};
    f32x4 accp[2] = {};

    const int lrow = lane >> 3;
    const int scol = ((lane & 7) * 16) ^ (lrow << 4);   // swizzled source byte col (A staging)

    // A staging bases (k-advance folds into imm offsets)
    const char* aS[4]; const char* xS[4];
#pragma unroll
    for (int r = 0; r < 4; ++r) {
        int row = (r * 4 + wv) * 8 + lrow;
        aS[r] = (const char*)hin + (size_t)(m0 + row) * (UNITS * 2) + scol;
        if (WARM) xS[r] = (const char*)xbf + (size_t)(m0 + row) * (T_IN * FEAT * 2) + (size_t)t * (FEAT * 2) + scol;
    }

    const int ar = lane & 15;
    const int ko = (lane >> 4) << 3;
    const int swz = (ar & 7) << 3;

    // B direct-load bases: frag ni = UT[n0+64wc+16ni+ar][kt*64 + kk*32 + ko .. +8)
    const char* bB[4];
#pragma unroll
    for (int ni = 0; ni < 4; ++ni)
        bB[ni] = (const char*)UT + ((size_t)(n0 + 64 * wc + 16 * ni + ar) * KD + ko) * 2;
    const char* wB = nullptr;
    if (PRED && doPred)
        wB = (const char*)WdT + ((size_t)(16 * nb + ar) * UNITS + ko) * 2;

    // epilogue geometry; bias preloaded (drained by first vmcnt)
    const int u16 = lane & 15;
    const int unit = (nb * 2 + wc) * 16 + u16;
    const int rbase = m0 + 64 * wr + ((lane >> 4) << 2);
    float bv[4];
#pragma unroll
    for (int g = 0; g < 4; ++g) bv[g] = bias[n0 + 64 * wc + 16 * g + u16];
    float bdv = 0.f;
    if (PRED && doPred) bdv = bd[16 * nb + u16];

    auto stageA = [&](int kt) {
        const int buf = kt & 1;
#pragma unroll
        for (int r = 0; r < 4; ++r) {
            const char* s = (WARM && kt == NKT - 1) ? xS[r] : (aS[r] + kt * 128);
            gl_lds16(s, (char*)Al + buf * 16384 + (r * 4 + wv) * 1024);
        }
    };

    bf16x8 Bf[8];
    bf16x8 Wf[2];
    auto loadB = [&](int kt) {
#pragma unroll
        for (int kk = 0; kk < 2; ++kk)
#pragma unroll
            for (int ni = 0; ni < 4; ++ni)
                Bf[kk * 4 + ni] = *reinterpret_cast<const bf16x8*>(bB[ni] + kt * 128 + kk * 64);
        if (PRED && doPred) {
#pragma unroll
            for (int kk = 0; kk < 2; ++kk)
                Wf[kk] = *reinterpret_cast<const bf16x8*>(wB + kt * 128 + kk * 64);
        }
    };

    auto compute = [&](int kt) {
        const int buf = kt & 1;
#pragma unroll
        for (int kk = 0; kk < 2; ++kk) {
            bf16x8 af[4];
#pragma unroll
            for (int mi = 0; mi < 4; ++mi)
                af[mi] = *reinterpret_cast<const bf16x8*>(&Al[buf * 8192 + (64 * wr + 16 * mi + ar) * 64 + ((32 * kk + ko) ^ swz)]);
#pragma unroll
            for (int mi = 0; mi < 4; ++mi)
#pragma unroll
                for (int ni = 0; ni < 4; ++ni)
                    acc[mi][ni] = __builtin_amdgcn_mfma_f32_16x16x32_bf16(af[mi], Bf[kk * 4 + ni], acc[mi][ni], 0, 0, 0);
            if (PRED && doPred) {
#pragma unroll
                for (int pi = 0; pi < 2; ++pi)
                    accp[pi] = __builtin_amdgcn_mfma_f32_16x16x32_bf16(af[2 * wc + pi], Wf[kk], accp[pi], 0, 0, 0);
            }
        }
    };

    // ---- pipelined K loop: A(kt) in LDS, B(kt) in regs; prefetch both for kt+1 ----
    stageA(0);
    loadB(0);
#pragma unroll
    for (int kt = 0; kt < NKT - 1; ++kt) {
        stageA(kt + 1);
        // wait everything except the 4 newest (A(kt+1) gl_lds): A(kt)+B(kt) done
        asm volatile("s_waitcnt vmcnt(4) lgkmcnt(0)" ::: "memory");
        __builtin_amdgcn_s_barrier();
        compute(kt);
        loadB(kt + 1);                      // overwrites Bf after last use (compiler-sequenced)
        __builtin_amdgcn_s_barrier();       // WAR on Al: keep waves within one iter
    }
    // final iter: prefetch c-state in the slot where A-staging would be
    float cv[16];
#pragma unroll
    for (int mi = 0; mi < 4; ++mi)
#pragma unroll
        for (int reg = 0; reg < 4; ++reg)
            cv[mi * 4 + reg] = cst[(size_t)(rbase + 16 * mi + reg) * UNITS + unit];
    asm volatile("s_waitcnt vmcnt(16) lgkmcnt(0)" ::: "memory");
    __builtin_amdgcn_s_barrier();
    compute(NKT - 1);

    // ---- shuffle-free gate epilogue: acc[mi][g] are i,f,g,o of this lane's unit ----
#pragma unroll
    for (int mi = 0; mi < 4; ++mi)
#pragma unroll
        for (int reg = 0; reg < 4; ++reg) {
            float zi = acc[mi][0][reg] + bv[0];
            float zf = acc[mi][1][reg] + bv[1];
            float zg = acc[mi][2][reg] + bv[2];
            float zo = acc[mi][3][reg] + bv[3];
            float cn = sigm(zf) * cv[mi * 4 + reg] + sigm(zi) * tanh_fast(zg);
            size_t idx = (size_t)(rbase + 16 * mi + reg) * UNITS + unit;
            cst[idx] = cn;
            hout[idx] = __float2bfloat16(sigm(zo) * tanh_fast(cn));
        }

    if (PRED && doPred) {
#pragma unroll
        for (int pi = 0; pi < 2; ++pi) {
            const int prow = m0 + 64 * wr + 32 * wc + 16 * pi + ((lane >> 4) << 2);
            f32x4 v = accp[pi];
#pragma unroll
            for (int reg = 0; reg < 4; ++reg)
                out[(size_t)(prow + reg) * (OUT_STEPS * FEAT) + (size_t)tstep * FEAT + (16 * nb + u16)] = v[reg] + bdv;
        }
    }
}

// ---------- host ----------
extern "C" void kernel_launch(void* const* d_in, const int* in_sizes, int n_in,
                              void* d_out, int out_size, void* d_ws, size_t ws_size,
                              hipStream_t stream) {
    const float* inputs = (const float*)d_in[0];
    const float* W  = (const float*)d_in[1];
    const float* U  = (const float*)d_in[2];
    const float* b  = (const float*)d_in[3];
    const float* Wd = (const float*)d_in[4];
    const float* bd = (const float*)d_in[5];
    float* out = (float*)d_out;

    char* ws = (char*)d_ws;
    size_t off = 0;
    auto alloc = [&](size_t bytes) { char* p = ws + off; off = (off + bytes + 255) & ~255ULL; return p; };
    __hip_bfloat16* UTw = (__hip_bfloat16*)alloc((size_t)GCOLS * KWARM * 2);
    __hip_bfloat16* UTd = (__hip_bfloat16*)alloc((size_t)GCOLS * UNITS * 2);
    __hip_bfloat16* WdT = (__hip_bfloat16*)alloc((size_t)FEAT * UNITS * 2);
    __hip_bfloat16* Xbf = (__hip_bfloat16*)alloc((size_t)B_SZ * T_IN * FEAT * 2);
    __hip_bfloat16* hA  = (__hip_bfloat16*)alloc((size_t)B_SZ * UNITS * 2);
    __hip_bfloat16* hB  = (__hip_bfloat16*)alloc((size_t)B_SZ * UNITS * 2);
    float* cst = (float*)alloc((size_t)B_SZ * UNITS * 4);
    float* bw  = (float*)alloc(GCOLS * 4);
    float* bdc = (float*)alloc(GCOLS * 4);

    hipMemsetAsync(cst, 0, (size_t)B_SZ * UNITS * 4, stream);
    hipMemsetAsync(hA, 0, (size_t)B_SZ * UNITS * 2, stream);

    dim3 blk(256);
    reorder_UW<<<dim3(17, 64), blk, 0, stream>>>(U, W, UTw);
    transpose_Wd<<<dim3(16), blk, 0, stream>>>(Wd, WdT);
    build_UTdec<<<dim3(4, 256), blk, 0, stream>>>(UTw, WdT, UTd);
    build_bias<<<dim3(16), blk, 0, stream>>>(b, bd, UTw, bw, bdc);
    {
        int n = B_SZ * T_IN * FEAT;
        convert_x<<<dim3((n + 255) / 256), blk, 0, stream>>>(inputs, Xbf, n);
    }

    const __hip_bfloat16* cur = hA;
    __hip_bfloat16* nxt = hB;
    for (int t = 0; t < T_IN; ++t) {
        lstm_step<true, false><<<dim3(512), blk, 0, stream>>>(cur, Xbf, t, UTw, bw, cst, nxt,
                                                              nullptr, nullptr, nullptr, 0);
        __hip_bfloat16* tmp = (__hip_bfloat16*)cur; cur = nxt; nxt = tmp;
    }
    // decode: kernel t consumes h_{t-1} (writes pred_{t-1}) and produces h_t
    for (int t = 1; t <= OUT_STEPS; ++t) {
        lstm_step<false, true><<<dim3(512), blk, 0, stream>>>(cur, nullptr, 0, UTd, bdc, cst, nxt,
                                                              WdT, bd, out, t - 1);
        __hip_bfloat16* tmp = (__hip_bfloat16*)cur; cur = nxt; nxt = tmp;
    }
}

// Round 6
// 4929.268 us; speedup vs baseline: 1.6804x; 1.6159x over previous
//
#include <hip/hip_runtime.h>
#include <hip/hip_bf16.h>

typedef float f32x4 __attribute__((ext_vector_type(4)));
typedef __bf16 bf16x8 __attribute__((ext_vector_type(8)));

#define B_SZ 2048
#define T_IN 48
#define FEAT 64
#define UNITS 1024
#define GCOLS 4096   // 4*UNITS
#define OUT_STEPS 64
#define KWARM 1088   // UNITS + FEAT

// Gate-major column permutation: c' = 64*Bk + 16*g + u  (Bk = 64-col half-block, g = gate, u = unit-low)
// original (Keras i,f,g,o) column: oc = g*1024 + (Bk*16 + u)
__device__ __forceinline__ int oc_of(int c) {
    return (((c >> 4) & 3) * UNITS) + ((c >> 6) * 16) + (c & 15);
}

typedef __attribute__((address_space(1))) const void gas_t;
typedef __attribute__((address_space(3))) void las_t;

__device__ __forceinline__ void gl_lds16(const void* g, void* l) {
    __builtin_amdgcn_global_load_lds((gas_t*)g, (las_t*)l, 16, 0, 0);
}
__device__ __forceinline__ float sigm(float x) {
    return __builtin_amdgcn_rcpf(1.0f + __expf(-x));
}
__device__ __forceinline__ float tanh_fast(float x) {
    float e = __expf(2.0f * x);
    return 1.0f - 2.0f * __builtin_amdgcn_rcpf(e + 1.0f);
}

// ---------- precompute kernels (unchanged, correctness-proven) ----------

__global__ __launch_bounds__(256) void reorder_UW(const float* __restrict__ U, const float* __restrict__ W,
                                                  __hip_bfloat16* __restrict__ UTw) {
    __shared__ __hip_bfloat16 t[64][64];
    const int k0 = blockIdx.x * 64;   // 17 tiles
    const int c0 = blockIdx.y * 64;   // 64 tiles
    const int tid = threadIdx.x;
#pragma unroll
    for (int i = 0; i < 16; ++i) {
        int idx = tid + i * 256;
        int rk = idx >> 6, cc = idx & 63;
        int k = k0 + rk, c = c0 + cc;
        int oc = oc_of(c);
        float v = (k < UNITS) ? U[(size_t)k * GCOLS + oc] : W[(size_t)(k - UNITS) * GCOLS + oc];
        t[rk][cc] = __float2bfloat16(v);
    }
    __syncthreads();
#pragma unroll
    for (int i = 0; i < 16; ++i) {
        int idx = tid + i * 256;
        int rc = idx >> 6, kk = idx & 63;
        UTw[(size_t)(c0 + rc) * KWARM + k0 + kk] = t[kk][rc];
    }
}

__global__ __launch_bounds__(256) void transpose_Wd(const float* __restrict__ Wd, __hip_bfloat16* __restrict__ WdT) {
    __shared__ __hip_bfloat16 t[64][64];
    const int k0 = blockIdx.x * 64;  // 16 blocks
    const int tid = threadIdx.x;
#pragma unroll
    for (int i = 0; i < 16; ++i) {
        int idx = tid + i * 256;
        int rk = idx >> 6, ff = idx & 63;
        t[rk][ff] = __float2bfloat16(Wd[(size_t)(k0 + rk) * FEAT + ff]);
    }
    __syncthreads();
#pragma unroll
    for (int i = 0; i < 16; ++i) {
        int idx = tid + i * 256;
        int rf = idx >> 6, kk = idx & 63;
        WdT[(size_t)rf * UNITS + k0 + kk] = t[kk][rf];
    }
}

__global__ __launch_bounds__(256) void build_UTdec(const __hip_bfloat16* __restrict__ UTw,
                                                   const __hip_bfloat16* __restrict__ WdT,
                                                   __hip_bfloat16* __restrict__ UTd) {
    __shared__ float Wl[64][16];
    const int k = blockIdx.x * 256 + threadIdx.x;  // 4 blocks
    const int c0 = blockIdx.y * 16;                // 256 blocks
    const int tid = threadIdx.x;
#pragma unroll
    for (int i = 0; i < 4; ++i) {
        int idx = tid + i * 256;
        int f = idx >> 4, cc = idx & 15;
        Wl[f][cc] = __bfloat162float(UTw[(size_t)(c0 + cc) * KWARM + UNITS + f]);
    }
    __syncthreads();
    float acc[16];
#pragma unroll
    for (int cc = 0; cc < 16; ++cc) acc[cc] = 0.f;
    for (int f = 0; f < 64; ++f) {
        float wd = __bfloat162float(WdT[(size_t)f * UNITS + k]);
#pragma unroll
        for (int cc = 0; cc < 16; ++cc) acc[cc] += wd * Wl[f][cc];
    }
#pragma unroll
    for (int cc = 0; cc < 16; ++cc) {
        float uv = __bfloat162float(UTw[(size_t)(c0 + cc) * KWARM + k]);
        UTd[(size_t)(c0 + cc) * UNITS + k] = __float2bfloat16(uv + acc[cc]);
    }
}

__global__ __launch_bounds__(256) void build_bias(const float* __restrict__ b, const float* __restrict__ bd,
                                                  const __hip_bfloat16* __restrict__ UTw,
                                                  float* __restrict__ bw, float* __restrict__ bdc) {
    const int c = blockIdx.x * 256 + threadIdx.x;  // 16 blocks
    const int oc = oc_of(c);
    float base = b[oc];
    float s = 0.f;
    for (int f = 0; f < FEAT; ++f) s += bd[f] * __bfloat162float(UTw[(size_t)c * KWARM + UNITS + f]);
    bw[c] = base;
    bdc[c] = base + s;
}

__global__ void convert_x(const float* __restrict__ x, __hip_bfloat16* __restrict__ xb, int n) {
    int i = blockIdx.x * blockDim.x + threadIdx.x;
    if (i < n) xb[i] = __float2bfloat16(x[i]);
}

// ---------- fused LSTM step ----------
// R6 = R3 structure (A+B via gl_lds dbuf, counted vmcnt, 2 barriers/iter,
// full unroll) with:
//  - DEFAULT linear block mapping (nb = bid&31): HW round-robin gives each
//    XCD 4 nb-slices -> 1MB of B, L2-resident across all decode steps
//    (R3's "rectangle" swizzle gave each XCD the whole B: FETCH 26->41.7MB)
//  - pred spread over nb<4 (accp[2], Wd frags via register loads; no Wl LDS)
//  - LDS 64KB (A 2x16 + B 2x16) -> 2 blocks/CU
template <bool WARM, bool PRED>
__global__ __launch_bounds__(256) void lstm_step(
    const __hip_bfloat16* __restrict__ hin,          // [2048][1024]
    const __hip_bfloat16* __restrict__ xbf, int t,   // [2048][48][64] (WARM)
    const __hip_bfloat16* __restrict__ UT,           // [4096][KD]
    const float* __restrict__ bias,                  // [4096] (c'-indexed)
    float* __restrict__ cst,                         // [2048][1024]
    __hip_bfloat16* __restrict__ hout,               // [2048][1024]
    const __hip_bfloat16* __restrict__ WdT,          // [64][1024] (PRED)
    const float* __restrict__ bd,                    // [64] (PRED)
    float* __restrict__ out, int tstep)              // [2048][64][64] (PRED)
{
    constexpr int KD = WARM ? KWARM : UNITS;
    constexpr int NKT = KD / 64;

    __shared__ alignas(16) __hip_bfloat16 Al[2 * 8192];   // 32 KB
    __shared__ alignas(16) __hip_bfloat16 Bl[2 * 8192];   // 32 KB

    const int tid = threadIdx.x;
    const int lane = tid & 63;
    const int wv = tid >> 6;
    const int wr = wv >> 1, wc = wv & 1;
    const int bid = blockIdx.x;
    const int nb = bid & 31;   // fastest -> round-robin across XCDs: B stays L2-resident
    const int mb = bid >> 5;
    const int m0 = mb * 128;
    const int n0 = nb * 128;
    const bool doPred = PRED && (nb < 4);

    f32x4 acc[4][4] = {};
    f32x4 accp[2] = {};

    const int lrow = lane >> 3;
    const int scol = ((lane & 7) * 16) ^ (lrow << 4);   // swizzled source byte col

    // loop-invariant staging bases (k-advance folds into imm offsets)
    const char* aS[4]; const char* bS[4]; const char* xS[4];
#pragma unroll
    for (int r = 0; r < 4; ++r) {
        int row = (r * 4 + wv) * 8 + lrow;
        aS[r] = (const char*)hin + (size_t)(m0 + row) * (UNITS * 2) + scol;
        bS[r] = (const char*)UT + (size_t)(n0 + row) * (KD * 2) + scol;
        if (WARM) xS[r] = (const char*)xbf + (size_t)(m0 + row) * (T_IN * FEAT * 2) + (size_t)t * (FEAT * 2) + scol;
    }

    const int ar = lane & 15;
    const int ko = (lane >> 4) << 3;
    const int swz = (ar & 7) << 3;

    // Wd fragments direct from global (L2-hot 128KB), one iter ahead in regs
    const char* wB = nullptr;
    if (PRED && doPred)
        wB = (const char*)WdT + ((size_t)(16 * nb + ar) * UNITS + ko) * 2;

    // epilogue geometry; bias preloaded (oldest VMEM ops, retired by first vmcnt)
    const int u16 = lane & 15;
    const int unit = (nb * 2 + wc) * 16 + u16;
    const int rbase = m0 + 64 * wr + ((lane >> 4) << 2);
    float bv[4];
#pragma unroll
    for (int g = 0; g < 4; ++g) bv[g] = bias[n0 + 64 * wc + 16 * g + u16];
    float bdv = 0.f;
    if (PRED && doPred) bdv = bd[16 * nb + u16];

    auto stage = [&](int kt) {
        const int buf = kt & 1;
#pragma unroll
        for (int r = 0; r < 4; ++r) {
            const char* s = (WARM && kt == NKT - 1) ? xS[r] : (aS[r] + kt * 128);
            gl_lds16(s, (char*)Al + buf * 16384 + (r * 4 + wv) * 1024);
        }
#pragma unroll
        for (int r = 0; r < 4; ++r)
            gl_lds16(bS[r] + kt * 128, (char*)Bl + buf * 16384 + (r * 4 + wv) * 1024);
    };

    bf16x8 Wf[2][2];   // [kt&1][kk] (kt compile-time via full unroll)
    auto loadWf = [&](int kt) {
        if (PRED && doPred) {
#pragma unroll
            for (int kk = 0; kk < 2; ++kk)
                Wf[kt & 1][kk] = *reinterpret_cast<const bf16x8*>(wB + kt * 128 + kk * 64);
        }
    };

    auto compute = [&](int kt) {
        const int buf = kt & 1;
#pragma unroll
        for (int kk = 0; kk < 2; ++kk) {
            bf16x8 af[4], bfr[4];
#pragma unroll
            for (int mi = 0; mi < 4; ++mi)
                af[mi] = *reinterpret_cast<const bf16x8*>(&Al[buf * 8192 + (64 * wr + 16 * mi + ar) * 64 + ((32 * kk + ko) ^ swz)]);
#pragma unroll
            for (int ni = 0; ni < 4; ++ni)
                bfr[ni] = *reinterpret_cast<const bf16x8*>(&Bl[buf * 8192 + (64 * wc + 16 * ni + ar) * 64 + ((32 * kk + ko) ^ swz)]);
#pragma unroll
            for (int mi = 0; mi < 4; ++mi)
#pragma unroll
                for (int ni = 0; ni < 4; ++ni)
                    acc[mi][ni] = __builtin_amdgcn_mfma_f32_16x16x32_bf16(af[mi], bfr[ni], acc[mi][ni], 0, 0, 0);
            if (PRED && doPred) {
#pragma unroll
                for (int pi = 0; pi < 2; ++pi)
                    accp[pi] = __builtin_amdgcn_mfma_f32_16x16x32_bf16(af[2 * wc + pi], Wf[kt & 1][kk], accp[pi], 0, 0, 0);
            }
        }
    };

    // ---- fully-unrolled pipelined K loop: stage(kt+1) in flight over compute(kt) ----
    stage(0);
    loadWf(0);
#pragma unroll
    for (int kt = 0; kt < NKT - 1; ++kt) {
        stage(kt + 1);
        loadWf(kt + 1);
        // retire stage(kt) [+Wf(kt)]; keep stage(kt+1) [+Wf(kt+1)] in flight
        if (PRED && doPred) asm volatile("s_waitcnt vmcnt(10) lgkmcnt(0)" ::: "memory");
        else                asm volatile("s_waitcnt vmcnt(8) lgkmcnt(0)" ::: "memory");
        __builtin_amdgcn_s_barrier();
        compute(kt);
        __builtin_amdgcn_s_barrier();   // WAR: protect buf before next re-stage
    }
    // final iter: prefetch c-state in the slot where staging would be
    float cv[16];
#pragma unroll
    for (int mi = 0; mi < 4; ++mi)
#pragma unroll
        for (int reg = 0; reg < 4; ++reg)
            cv[mi * 4 + reg] = cst[(size_t)(rbase + 16 * mi + reg) * UNITS + unit];
    asm volatile("s_waitcnt vmcnt(16) lgkmcnt(0)" ::: "memory");
    __builtin_amdgcn_s_barrier();
    compute(NKT - 1);

    // ---- shuffle-free gate epilogue: acc[mi][g] are i,f,g,o of this lane's unit ----
#pragma unroll
    for (int mi = 0; mi < 4; ++mi)
#pragma unroll
        for (int reg = 0; reg < 4; ++reg) {
            float zi = acc[mi][0][reg] + bv[0];
            float zf = acc[mi][1][reg] + bv[1];
            float zg = acc[mi][2][reg] + bv[2];
            float zo = acc[mi][3][reg] + bv[3];
            float cn = sigm(zf) * cv[mi * 4 + reg] + sigm(zi) * tanh_fast(zg);
            size_t idx = (size_t)(rbase + 16 * mi + reg) * UNITS + unit;
            cst[idx] = cn;
            hout[idx] = __float2bfloat16(sigm(zo) * tanh_fast(cn));
        }

    if (PRED && doPred) {
#pragma unroll
        for (int pi = 0; pi < 2; ++pi) {
            const int prow = m0 + 64 * wr + 32 * wc + 16 * pi + ((lane >> 4) << 2);
            f32x4 v = accp[pi];
#pragma unroll
            for (int reg = 0; reg < 4; ++reg)
                out[(size_t)(prow + reg) * (OUT_STEPS * FEAT) + (size_t)tstep * FEAT + (16 * nb + u16)] = v[reg] + bdv;
        }
    }
}

// ---------- host ----------
extern "C" void kernel_launch(void* const* d_in, const int* in_sizes, int n_in,
                              void* d_out, int out_size, void* d_ws, size_t ws_size,
                              hipStream_t stream) {
    const float* inputs = (const float*)d_in[0];
    const float* W  = (const float*)d_in[1];
    const float* U  = (const float*)d_in[2];
    const float* b  = (const float*)d_in[3];
    const float* Wd = (const float*)d_in[4];
    const float* bd = (const float*)d_in[5];
    float* out = (float*)d_out;

    char* ws = (char*)d_ws;
    size_t off = 0;
    auto alloc = [&](size_t bytes) { char* p = ws + off; off = (off + bytes + 255) & ~255ULL; return p; };
    __hip_bfloat16* UTw = (__hip_bfloat16*)alloc((size_t)GCOLS * KWARM * 2);
    __hip_bfloat16* UTd = (__hip_bfloat16*)alloc((size_t)GCOLS * UNITS * 2);
    __hip_bfloat16* WdT = (__hip_bfloat16*)alloc((size_t)FEAT * UNITS * 2);
    __hip_bfloat16* Xbf = (__hip_bfloat16*)alloc((size_t)B_SZ * T_IN * FEAT * 2);
    __hip_bfloat16* hA  = (__hip_bfloat16*)alloc((size_t)B_SZ * UNITS * 2);
    __hip_bfloat16* hB  = (__hip_bfloat16*)alloc((size_t)B_SZ * UNITS * 2);
    float* cst = (float*)alloc((size_t)B_SZ * UNITS * 4);
    float* bw  = (float*)alloc(GCOLS * 4);
    float* bdc = (float*)alloc(GCOLS * 4);

    hipMemsetAsync(cst, 0, (size_t)B_SZ * UNITS * 4, stream);
    hipMemsetAsync(hA, 0, (size_t)B_SZ * UNITS * 2, stream);

    dim3 blk(256);
    reorder_UW<<<dim3(17, 64), blk, 0, stream>>>(U, W, UTw);
    transpose_Wd<<<dim3(16), blk, 0, stream>>>(Wd, WdT);
    build_UTdec<<<dim3(4, 256), blk, 0, stream>>>(UTw, WdT, UTd);
    build_bias<<<dim3(16), blk, 0, stream>>>(b, bd, UTw, bw, bdc);
    {
        int n = B_SZ * T_IN * FEAT;
        convert_x<<<dim3((n + 255) / 256), blk, 0, stream>>>(inputs, Xbf, n);
    }

    const __hip_bfloat16* cur = hA;
    __hip_bfloat16* nxt = hB;
    for (int t = 0; t < T_IN; ++t) {
        lstm_step<true, false><<<dim3(512), blk, 0, stream>>>(cur, Xbf, t, UTw, bw, cst, nxt,
                                                              nullptr, nullptr, nullptr, 0);
        __hip_bfloat16* tmp = (__hip_bfloat16*)cur; cur = nxt; nxt = tmp;
    }
    // decode: kernel t consumes h_{t-1} (writes pred_{t-1}) and produces h_t
    for (int t = 1; t <= OUT_STEPS; ++t) {
        lstm_step<false, true><<<dim3(512), blk, 0, stream>>>(cur, nullptr, 0, UTd, bdc, cst, nxt,
                                                              WdT, bd, out, t - 1);
        __hip_bfloat16* tmp = (__hip_bfloat16*)cur; cur = nxt; nxt = tmp;
    }
}